// Round 4
// baseline (143.908 us; speedup 1.0000x reference)
//
#include <hip/hip_runtime.h>
#include <math.h>

#define G 16
#define HS 396          // hbuf row stride (floats)
#define LSTR 232        // latb row stride (bf16): 464B, 16B-aligned, 2-way-bank only

typedef __attribute__((ext_vector_type(8))) __bf16 bf16x8;
typedef __attribute__((ext_vector_type(4))) float f32x4;
typedef __attribute__((ext_vector_type(2))) float f32x2;

// ---------------- Kernel W: swizzle w_fc (392x224 fp32) into bf16 MFMA B-fragments ----------
// wb[((tile*7 + kt)*64 + lane)*8 + j] = bf16(w_fc[n][k]), n = tile*16 + (lane&15),
// k = kt*32 + (lane>>4)*8 + j.  Tiles 0..24 (N padded 392->400 with zeros).
__global__ void wconv_kernel(const float* __restrict__ w_fc, __bf16* __restrict__ wb) {
  int tile = blockIdx.x;      // 0..24
  int kt   = blockIdx.y;      // 0..6
  int lane = threadIdx.x;     // 0..63
  int n  = tile * 16 + (lane & 15);
  int k0 = kt * 32 + (lane >> 4) * 8;
  bf16x8 v;
  if (n < 392) {
    const float* src = w_fc + (size_t)n * 224 + k0;
    float4 f0 = *(const float4*)(src);
    float4 f1 = *(const float4*)(src + 4);
    v[0] = (__bf16)f0.x; v[1] = (__bf16)f0.y; v[2] = (__bf16)f0.z; v[3] = (__bf16)f0.w;
    v[4] = (__bf16)f1.x; v[5] = (__bf16)f1.y; v[6] = (__bf16)f1.z; v[7] = (__bf16)f1.w;
  } else {
    #pragma unroll
    for (int j = 0; j < 8; ++j) v[j] = (__bf16)0.f;
  }
  *(bf16x8*)(wb + ((size_t)(tile * 7 + kt) * 64 + lane) * 8) = v;
}

// ---------------- Fused kernel: one block = 16 samples, end to end ----------------
// Phase 0: quadrant means (wave wv owns samples wv*4..wv*4+3; nontemporal float4 stream)
// Phase 1: 4-qubit sim on threads t<16 (LDS in/out, no global round-trip)
// Phase 2: latent = relu(qf @ w_lat^T + b_lat) -> bf16 LDS
// Phase 3: h = relu(latent @ w_fc^T + b_fc) via 25x7 mfma_f32_16x16x32_bf16
// Phase 4: deconv1+relu+deconv2+sigmoid, nontemporal float2 stores
__global__ __launch_bounds__(256, 4) void fused_kernel(
    const float* __restrict__ x, const float* __restrict__ params,
    const __bf16* __restrict__ wb,
    const float* __restrict__ w_lat, const float* __restrict__ b_lat,
    const float* __restrict__ b_fc,
    const float* __restrict__ w_d1, const float* __restrict__ b_d1,
    const float* __restrict__ w_d2, const float* __restrict__ b_d2,
    float* __restrict__ out, int B)
{
  __shared__ __align__(16) __bf16 latb[G * LSTR];
  __shared__ __align__(16) float hbuf[G * HS];
  __shared__ float qfs[G * 4];       // means, then overwritten with <Z_q> features
  __shared__ float wd1[128];
  __shared__ float wd2[16];
  __shared__ float bd1[4];
  const int t = threadIdx.x;
  const int wv = t >> 6;
  const int lane = t & 63;
  const int s0g = blockIdx.x * G;
  if (s0g >= B) return;

  if (t < 128) wd1[t] = w_d1[t];
  else if (t < 144) wd2[t - 128] = w_d2[t - 128];
  else if (t < 148) bd1[t - 144] = b_d1[t - 144];

  // ---- Phase 0: quadrant sums. Wave wv handles 4 samples; per-element quadrant
  // weights depend only on i4 (same for all samples) so hoist them.
  {
    const float* xb = x + (size_t)(s0g + wv * 4) * 784;
    float acc[4][4];   // [smp][quad: TL,TR,BL,BR]
    #pragma unroll
    for (int i = 0; i < 4; ++i)
      #pragma unroll
      for (int q = 0; q < 4; ++q) acc[i][q] = 0.f;
    for (int i4 = lane; i4 < 196; i4 += 64) {
      int base = i4 * 4;
      int r = base / 28;
      int cb = base - r * 28;          // float4 never crosses a row (28 % 4 == 0)
      float bt = (r >= 14) ? 1.f : 0.f;
      float tp = 1.f - bt;
      float w0[4], w1[4], w2[4], w3[4];
      #pragma unroll
      for (int e = 0; e < 4; ++e) {
        float lf = ((cb + e) < 14) ? 1.f : 0.f;
        float rf = 1.f - lf;
        w0[e] = tp * lf; w1[e] = tp * rf; w2[e] = bt * lf; w3[e] = bt * rf;
      }
      #pragma unroll
      for (int smp = 0; smp < 4; ++smp) {
        f32x4 v = __builtin_nontemporal_load((const f32x4*)(xb + smp * 784 + base));
        #pragma unroll
        for (int e = 0; e < 4; ++e) {
          acc[smp][0] = fmaf(v[e], w0[e], acc[smp][0]);
          acc[smp][1] = fmaf(v[e], w1[e], acc[smp][1]);
          acc[smp][2] = fmaf(v[e], w2[e], acc[smp][2]);
          acc[smp][3] = fmaf(v[e], w3[e], acc[smp][3]);
        }
      }
    }
    #pragma unroll
    for (int smp = 0; smp < 4; ++smp)
      #pragma unroll
      for (int q = 0; q < 4; ++q)
        #pragma unroll
        for (int o = 32; o > 0; o >>= 1)
          acc[smp][q] += __shfl_down(acc[smp][q], o, 64);
    if (lane == 0) {
      const float inv = 1.f / 196.f;
      #pragma unroll
      for (int smp = 0; smp < 4; ++smp) {
        float4 o;
        o.x = acc[smp][0] * inv; o.y = acc[smp][1] * inv;
        o.z = acc[smp][2] * inv; o.w = acc[smp][3] * inv;
        *(float4*)(qfs + (wv * 4 + smp) * 4) = o;
      }
    }
  }
  __syncthreads();

  // ---- Phase 1: 4-qubit statevector sim, thread t simulates sample t (t<16).
  if (t < G) {
    float means[4] = {qfs[t * 4], qfs[t * 4 + 1], qfs[t * 4 + 2], qfs[t * 4 + 3]};
    float cs[4], sn[4];
    #pragma unroll
    for (int q = 0; q < 4; ++q) {
      float th = 0.5f * means[q];
      sn[q] = __sinf(th);
      cs[q] = __cosf(th);
    }
    float re[16], im[16];
    #pragma unroll
    for (int idx = 0; idx < 16; ++idx) {
      float a = ((idx >> 3) & 1) ? sn[0] : cs[0];
      a *= ((idx >> 2) & 1) ? sn[1] : cs[1];
      a *= ((idx >> 1) & 1) ? sn[2] : cs[2];
      a *= (idx & 1) ? sn[3] : cs[3];
      re[idx] = a;
      im[idx] = 0.f;
    }
    #pragma unroll
    for (int q = 0; q < 4; ++q) {
      float hp = 0.5f * params[q];
      float sp = __sinf(hp), cp = __cosf(hp);
      int qb = 3 - q;
      #pragma unroll
      for (int idx = 0; idx < 16; ++idx) {
        float sg = ((idx >> qb) & 1) ? sp : -sp;   // exp(+-i p/2)
        float r0 = re[idx], i0 = im[idx];
        re[idx] = r0 * cp - i0 * sg;
        im[idx] = r0 * sg + i0 * cp;
      }
      int cm = 1 << qb;
      int tm = 1 << (3 - ((q + 1) & 3));
      #pragma unroll
      for (int idx = 0; idx < 16; ++idx) {
        if ((idx & cm) && !(idx & tm)) {
          int j = idx | tm;
          float tr = re[idx]; re[idx] = re[j]; re[j] = tr;
          float ti = im[idx]; im[idx] = im[j]; im[j] = ti;
        }
      }
    }
    #pragma unroll
    for (int q = 0; q < 4; ++q) {
      int qb = 3 - q;
      float z = 0.f;
      #pragma unroll
      for (int idx = 0; idx < 16; ++idx) {
        float p = re[idx] * re[idx] + im[idx] * im[idx];
        z += ((idx >> qb) & 1) ? -p : p;
      }
      qfs[t * 4 + q] = z;
    }
  }
  __syncthreads();

  // ---- Phase 2: latent[s][j] = relu(qf[s] . w_lat[j] + b_lat[j]) -> bf16 LDS
  for (int v = t; v < G * 224; v += 256) {
    int s = v / 224;
    int j = v - s * 224;
    float4 w = *(const float4*)(w_lat + j * 4);
    float a = b_lat[j];
    a = fmaf(qfs[s * 4 + 0], w.x, a);
    a = fmaf(qfs[s * 4 + 1], w.y, a);
    a = fmaf(qfs[s * 4 + 2], w.z, a);
    a = fmaf(qfs[s * 4 + 3], w.w, a);
    latb[s * LSTR + j] = (__bf16)fmaxf(a, 0.f);
  }
  __syncthreads();

  // ---- Phase 3: MFMA. wave wv handles N-tiles wv, wv+4, ...
  {
    const int m = lane & 15;       // A-row (sample) AND B/D-col (n) index
    const int kq = lane >> 4;      // k-quad
    const __bf16* arow = latb + m * LSTR + kq * 8;
    for (int tile = wv; tile < 25; tile += 4) {
      f32x4 acc = {0.f, 0.f, 0.f, 0.f};
      const bf16x8* bp = (const bf16x8*)(wb + ((size_t)(tile * 7) * 64 + lane) * 8);
      #pragma unroll
      for (int kt = 0; kt < 7; ++kt) {
        bf16x8 a = *(const bf16x8*)(arow + kt * 32);
        bf16x8 b = bp[kt * 64];
        acc = __builtin_amdgcn_mfma_f32_16x16x32_bf16(a, b, acc, 0, 0, 0);
      }
      int j = tile * 16 + m;
      if (j < 392) {
        float bf = b_fc[j];
        #pragma unroll
        for (int r = 0; r < 4; ++r)
          hbuf[(kq * 4 + r) * HS + j] = fmaxf(acc[r] + bf, 0.f);
      }
    }
  }
  __syncthreads();

  // ---- Phase 4: deconv1(8->4, k=s=2) + relu + deconv2(4->1, k=s=2) + sigmoid.
  const float bd2v = b_d2[0];
  for (int v = t; v < G * 196; v += 256) {
    int s = v / 196;
    int p = v - s * 196;
    int Y = p / 14;
    int X = p - Y * 14;
    int y = Y >> 1, ey = Y & 1, xx = X >> 1, ex = X & 1;
    const float* hs = hbuf + s * HS + y * 7 + xx;
    float hv[8];
    #pragma unroll
    for (int ci = 0; ci < 8; ++ci) hv[ci] = hs[ci * 49];
    float o1[4];
    #pragma unroll
    for (int co = 0; co < 4; ++co) {
      float a = bd1[co];
      #pragma unroll
      for (int ci = 0; ci < 8; ++ci)
        a = fmaf(hv[ci], wd1[ci * 16 + co * 4 + ey * 2 + ex], a);
      o1[co] = fmaxf(a, 0.f);
    }
    size_t basep = (size_t)(s0g + s) * 784;
    #pragma unroll
    for (int dy = 0; dy < 2; ++dy) {
      float v0 = bd2v, v1 = bd2v;
      #pragma unroll
      for (int co = 0; co < 4; ++co) {
        v0 = fmaf(o1[co], wd2[co * 4 + dy * 2 + 0], v0);
        v1 = fmaf(o1[co], wd2[co * 4 + dy * 2 + 1], v1);
      }
      f32x2 o;
      o[0] = 1.f / (1.f + __expf(-v0));
      o[1] = 1.f / (1.f + __expf(-v1));
      __builtin_nontemporal_store(o, (f32x2*)(out + basep + (size_t)(2 * Y + dy) * 28 + 2 * X));
    }
  }
}

extern "C" void kernel_launch(void* const* d_in, const int* in_sizes, int n_in,
                              void* d_out, int out_size, void* d_ws, size_t ws_size,
                              hipStream_t stream) {
  const float* x          = (const float*)d_in[0];
  const float* var_params = (const float*)d_in[1];
  const float* w_lat      = (const float*)d_in[2];
  const float* b_lat      = (const float*)d_in[3];
  const float* w_fc       = (const float*)d_in[4];
  const float* b_fc       = (const float*)d_in[5];
  const float* w_d1       = (const float*)d_in[6];
  const float* b_d1       = (const float*)d_in[7];
  const float* w_d2       = (const float*)d_in[8];
  const float* b_d2       = (const float*)d_in[9];
  float* out = (float*)d_out;

  __bf16* wb = (__bf16*)d_ws;   // 25*7*64*8 bf16 = 179200 B of swizzled w_fc fragments

  int B = in_sizes[0] / 784;
  wconv_kernel<<<dim3(25, 7), 64, 0, stream>>>(w_fc, wb);
  fused_kernel<<<(B + G - 1) / G, 256, 0, stream>>>(
      x, var_params, wb, w_lat, b_lat, b_fc, w_d1, b_d1, w_d2, b_d2, out, B);
}